// Round 3
// baseline (352.408 us; speedup 1.0000x reference)
//
#include <hip/hip_runtime.h>
#include <math.h>

#define N_TOKENS 32768
#define D_MODEL  1024
#define N_EXPERT 16
#define T        16               // tokens per block
#define NBLK     (N_TOKENS / T)   // 2048
#define PF       8                // prefetch depth

// d_out layout (float32, concatenated outputs):
//   [0, 65536)       top_k_indices as floats, row-major [N,2]
//   [65536, 131072)  top_k_scores,            row-major [N,2]
//   [131072]         loss scalar
// d_ws: 32 floats: [0,16) expert counts, [16,32) prob sums

__global__ __launch_bounds__(256, 2)
void gate_kernel(const float* __restrict__ inp,
                 const float* __restrict__ W,
                 float* __restrict__ out,
                 float* __restrict__ acc)
{
    const int tid  = threadIdx.x;
    const int wave = tid >> 6;
    const int lane = tid & 63;
    const int d0   = wave * 256 + lane * 4;   // this lane's 4 dims
    const int tok0 = blockIdx.x * T;

    // W fragment: W[e][d0..d0+3] for all 16 experts = 64 VGPRs.
    // Coalesced: per e, 64 lanes read 1KB contiguous.
    float4 wreg[N_EXPERT];
    #pragma unroll
    for (int e = 0; e < N_EXPERT; ++e)
        wreg[e] = *reinterpret_cast<const float4*>(W + e * D_MODEL + d0);

    // lds_part[t][sub][e]: partial logit over 64-dim subgroup; sub = wave*4 + (lane>>4)
    __shared__ float lds_part[T][16][N_EXPERT];
    __shared__ float lds_cnt[T][N_EXPERT];
    __shared__ float lds_ps[T][N_EXPERT];

    // 8-deep prefetch ring (all indices static after full unroll)
    float4 x[PF];
    #pragma unroll
    for (int t = 0; t < PF; ++t)
        x[t] = *reinterpret_cast<const float4*>(inp + (size_t)(tok0 + t) * D_MODEL + d0);

    #pragma unroll
    for (int t = 0; t < T; ++t) {
        float4 xv = x[t & (PF - 1)];
        if (t + PF < T)
            x[t & (PF - 1)] = *reinterpret_cast<const float4*>(
                inp + (size_t)(tok0 + t + PF) * D_MODEL + d0);

        // 64 FMAs: partial dot for all 16 experts over this lane's 4 dims
        float vals[N_EXPERT];
        #pragma unroll
        for (int e = 0; e < N_EXPERT; ++e)
            vals[e] = xv.x * wreg[e].x + xv.y * wreg[e].y
                    + xv.z * wreg[e].z + xv.w * wreg[e].w;

        // Butterfly transpose-reduce (masks 8,4,2,1): after this, lane l holds
        // sum over its 16-lane subgroup of vals[l&15].
        #pragma unroll
        for (int m = 8; m >= 1; m >>= 1) {
            const bool hi = (lane & m) != 0;
            float nv[8];
            #pragma unroll
            for (int k = 0; k < m; ++k) {
                float mine = hi ? vals[k + m] : vals[k];
                float oth  = hi ? vals[k]     : vals[k + m];
                nv[k] = mine + __shfl_xor(oth, m);
            }
            #pragma unroll
            for (int k = 0; k < m; ++k) vals[k] = nv[k];
        }
        // All 64 lanes write contiguous floats -> 2-way bank alias (free)
        lds_part[t][wave * 4 + (lane >> 4)][lane & 15] = vals[0];
    }

    __syncthreads();

    // Phase B: 16 tokens x 16 expert-lanes in parallel: sum 16 subgroup
    // partials, then top-2 merge butterfly + 2-way softmax.
    {
        const int tgrp = tid >> 4;    // token within block
        const int el   = tid & 15;    // expert lane
        float v1 = 0.f;
        #pragma unroll
        for (int g = 0; g < 16; ++g) v1 += lds_part[tgrp][g][el];

        int   i1 = el;
        float v2 = -INFINITY;
        int   i2 = 0;
        #pragma unroll
        for (int m = 1; m <= 8; m <<= 1) {
            float o1 = __shfl_xor(v1, m);
            int  oi1 = __shfl_xor(i1, m);
            float o2 = __shfl_xor(v2, m);
            int  oi2 = __shfl_xor(i2, m);
            // (val desc, idx asc) — matches jax.lax.top_k tie order
            bool afirst = (v1 > o1) || (v1 == o1 && i1 < oi1);
            float c1v = afirst ? v1 : o1;   int c1i = afirst ? i1 : oi1;
            float bv  = afirst ? o1 : v1;   int bi  = afirst ? oi1 : i1;
            float sv  = afirst ? v2 : o2;   int si  = afirst ? i2 : oi2;
            bool sgt  = (bv > sv) || (bv == sv && bi < si);
            v1 = c1v; i1 = c1i;
            v2 = sgt ? bv : sv;  i2 = sgt ? bi : si;
        }
        float tt = expf(v2 - v1);
        float p1 = 1.f / (1.f + tt);
        float p2 = tt * p1;
        const int tok = tok0 + tgrp;
        if (el == 0) {
            *reinterpret_cast<float2*>(out + 2 * tok) =
                make_float2((float)i1, (float)i2);
            *reinterpret_cast<float2*>(out + 2 * N_TOKENS + 2 * tok) =
                make_float2(p1, p2);
        }
        lds_cnt[tgrp][el] = (el == i1 ? 1.f : 0.f) + (el == i2 ? 1.f : 0.f);
        lds_ps [tgrp][el] = (el == i1 ? p1 : 0.f) + (el == i2 ? p2 : 0.f);
    }
    __syncthreads();

    // Block-level reduce of counts / prob-sums, then 32 global atomics.
    if (tid < 32) {
        const int el = tid & 15;
        float ssum = 0.f;
        if (tid < 16) {
            #pragma unroll
            for (int g = 0; g < T; ++g) ssum += lds_cnt[g][el];
            atomicAdd(&acc[el], ssum);
        } else {
            #pragma unroll
            for (int g = 0; g < T; ++g) ssum += lds_ps[g][el];
            atomicAdd(&acc[N_EXPERT + el], ssum);
        }
    }
}

__global__ void loss_kernel(const float* __restrict__ acc, float* __restrict__ out)
{
    if (threadIdx.x == 0) {
        float sum = 0.f;
        #pragma unroll
        for (int e = 0; e < N_EXPERT; ++e)
            sum += acc[e] * acc[N_EXPERT + e];
        out[4 * N_TOKENS] = sum * (float)N_EXPERT
                          / ((float)N_TOKENS * (float)N_TOKENS);
    }
}

extern "C" void kernel_launch(void* const* d_in, const int* in_sizes, int n_in,
                              void* d_out, int out_size, void* d_ws, size_t ws_size,
                              hipStream_t stream)
{
    const float* inp = (const float*)d_in[0];
    const float* W   = (const float*)d_in[1];
    float* out = (float*)d_out;
    float* acc = (float*)d_ws;

    hipMemsetAsync(acc, 0, 32 * sizeof(float), stream);
    gate_kernel<<<NBLK, 256, 0, stream>>>(inp, W, out, acc);
    loss_kernel<<<1, 64, 0, stream>>>(acc, out);
}

// Round 4
// 44.891 us; speedup vs baseline: 7.8503x; 7.8503x over previous
//
#include <hip/hip_runtime.h>
#include <math.h>

#define N_TOKENS 32768
#define D_MODEL  1024
#define N_EXPERT 16
#define T        16               // tokens per block
#define NBLK     (N_TOKENS / T)   // 2048
#define NBANK    64               // accumulator banks (contention spreader)

// d_out layout (float32, concatenated outputs):
//   [0, 65536)       top_k_indices as floats, row-major [N,2]
//   [65536, 131072)  top_k_scores,            row-major [N,2]
//   [131072]         loss scalar
// d_ws: NBANK*32 floats: bank b: [b*32+0 .. +15] counts, [b*32+16 .. +31] prob sums

__global__ __launch_bounds__(256, 2)
void gate_kernel(const float* __restrict__ inp,
                 const float* __restrict__ W,
                 float* __restrict__ out,
                 float* __restrict__ acc)
{
    const int tid  = threadIdx.x;
    const int wave = tid >> 6;
    const int lane = tid & 63;
    const int d0   = wave * 256 + lane * 4;   // this lane's 4 dims
    const int tok0 = blockIdx.x * T;
    const bool hi8 = (lane & 8) != 0;
    const bool hi4 = (lane & 4) != 0;
    const bool hi2 = (lane & 2) != 0;
    const bool hi1 = (lane & 1) != 0;

    // W fragment: W[e][d0..d0+3] for all 16 experts = 64 VGPRs, loaded once.
    float4 wreg[N_EXPERT];
    #pragma unroll
    for (int e = 0; e < N_EXPERT; ++e)
        wreg[e] = *reinterpret_cast<const float4*>(W + e * D_MODEL + d0);

    __shared__ float lds_part[T][4][N_EXPERT];   // [token][wave][expert]
    __shared__ float lds_cnt[T][N_EXPERT];
    __shared__ float lds_ps[T][N_EXPERT];

    const float* xptr = inp + (size_t)tok0 * D_MODEL + d0;

#define LOADX(xr, t) xr = *reinterpret_cast<const float4*>(xptr + (t) * D_MODEL);

#define DOT(xv, e) (xv.x*wreg[e].x + xv.y*wreg[e].y + xv.z*wreg[e].z + xv.w*wreg[e].w)

    // Transpose-reduce with named scalars only (no private arrays -> no scratch).
    // After masks 8,4,2,1,16,32: s0 = full 256-dim wave partial of expert (lane&15).
#define DOTOK(xv, t) do { \
    float a0 =DOT(xv,0),  a1 =DOT(xv,1),  a2 =DOT(xv,2),  a3 =DOT(xv,3);  \
    float a4 =DOT(xv,4),  a5 =DOT(xv,5),  a6 =DOT(xv,6),  a7 =DOT(xv,7);  \
    float a8 =DOT(xv,8),  a9 =DOT(xv,9),  a10=DOT(xv,10), a11=DOT(xv,11); \
    float a12=DOT(xv,12), a13=DOT(xv,13), a14=DOT(xv,14), a15=DOT(xv,15); \
    float b0 = (hi8 ? a8  : a0) + __shfl_xor(hi8 ? a0 : a8 , 8); \
    float b1 = (hi8 ? a9  : a1) + __shfl_xor(hi8 ? a1 : a9 , 8); \
    float b2 = (hi8 ? a10 : a2) + __shfl_xor(hi8 ? a2 : a10, 8); \
    float b3 = (hi8 ? a11 : a3) + __shfl_xor(hi8 ? a3 : a11, 8); \
    float b4 = (hi8 ? a12 : a4) + __shfl_xor(hi8 ? a4 : a12, 8); \
    float b5 = (hi8 ? a13 : a5) + __shfl_xor(hi8 ? a5 : a13, 8); \
    float b6 = (hi8 ? a14 : a6) + __shfl_xor(hi8 ? a6 : a14, 8); \
    float b7 = (hi8 ? a15 : a7) + __shfl_xor(hi8 ? a7 : a15, 8); \
    float c0 = (hi4 ? b4 : b0) + __shfl_xor(hi4 ? b0 : b4, 4); \
    float c1 = (hi4 ? b5 : b1) + __shfl_xor(hi4 ? b1 : b5, 4); \
    float c2 = (hi4 ? b6 : b2) + __shfl_xor(hi4 ? b2 : b6, 4); \
    float c3 = (hi4 ? b7 : b3) + __shfl_xor(hi4 ? b3 : b7, 4); \
    float e0 = (hi2 ? c2 : c0) + __shfl_xor(hi2 ? c0 : c2, 2); \
    float e1 = (hi2 ? c3 : c1) + __shfl_xor(hi2 ? c1 : c3, 2); \
    float s0 = (hi1 ? e1 : e0) + __shfl_xor(hi1 ? e0 : e1, 1); \
    s0 += __shfl_xor(s0, 16); \
    s0 += __shfl_xor(s0, 32); \
    if (lane < N_EXPERT) lds_part[t][wave][lane] = s0; \
} while (0)

    // Software pipeline: 4 named prefetch regs, distance 4 tokens.
    float4 x0, x1, x2, x3;
    LOADX(x0, 0) LOADX(x1, 1) LOADX(x2, 2) LOADX(x3, 3)
    for (int g = 0; g < 3; ++g) {
        const int tb = g * 4;
        DOTOK(x0, tb + 0); LOADX(x0, tb + 4)
        DOTOK(x1, tb + 1); LOADX(x1, tb + 5)
        DOTOK(x2, tb + 2); LOADX(x2, tb + 6)
        DOTOK(x3, tb + 3); LOADX(x3, tb + 7)
    }
    DOTOK(x0, 12); DOTOK(x1, 13); DOTOK(x2, 14); DOTOK(x3, 15);

    __syncthreads();

    // Phase B: 16 tokens x 16 expert-lanes: sum 4 wave partials, top-2
    // merge butterfly ((val desc, idx asc) == jax.lax.top_k), 2-way softmax.
    {
        const int tgrp = tid >> 4;
        const int el   = tid & 15;
        float v1 = lds_part[tgrp][0][el] + lds_part[tgrp][1][el]
                 + lds_part[tgrp][2][el] + lds_part[tgrp][3][el];
        int   i1 = el;
        float v2 = -INFINITY;
        int   i2 = 0;
        #pragma unroll
        for (int m = 1; m <= 8; m <<= 1) {
            float o1 = __shfl_xor(v1, m);
            int  oi1 = __shfl_xor(i1, m);
            float o2 = __shfl_xor(v2, m);
            int  oi2 = __shfl_xor(i2, m);
            bool afirst = (v1 > o1) || (v1 == o1 && i1 < oi1);
            float c1v = afirst ? v1 : o1;   int c1i = afirst ? i1 : oi1;
            float bv  = afirst ? o1 : v1;   int bi  = afirst ? oi1 : i1;
            float sv  = afirst ? v2 : o2;   int si  = afirst ? i2 : oi2;
            bool sgt  = (bv > sv) || (bv == sv && bi < si);
            v1 = c1v; i1 = c1i;
            v2 = sgt ? bv : sv;  i2 = sgt ? bi : si;
        }
        float tt = expf(v2 - v1);
        float p1 = 1.f / (1.f + tt);
        float p2 = tt * p1;
        const int tok = tok0 + tgrp;
        if (el == 0) {
            *reinterpret_cast<float2*>(out + 2 * tok) =
                make_float2((float)i1, (float)i2);
            *reinterpret_cast<float2*>(out + 2 * N_TOKENS + 2 * tok) =
                make_float2(p1, p2);
        }
        lds_cnt[tgrp][el] = (el == i1 ? 1.f : 0.f) + (el == i2 ? 1.f : 0.f);
        lds_ps [tgrp][el] = (el == i1 ? p1 : 0.f) + (el == i2 ? p2 : 0.f);
    }
    __syncthreads();

    // Block-level reduce, then one banked atomic per thread (tid<32).
    if (tid < 32) {
        const int el = tid & 15;
        float ssum = 0.f;
        if (tid < 16) {
            #pragma unroll
            for (int g = 0; g < T; ++g) ssum += lds_cnt[g][el];
        } else {
            #pragma unroll
            for (int g = 0; g < T; ++g) ssum += lds_ps[g][el];
        }
        atomicAdd(&acc[(blockIdx.x & (NBANK - 1)) * 32 + tid], ssum);
    }
#undef LOADX
#undef DOT
#undef DOTOK
}

__global__ void loss_kernel(const float* __restrict__ acc, float* __restrict__ out)
{
    __shared__ float partial[8][32];
    __shared__ float col[32];
    const int tid = threadIdx.x;   // 256
    const int c   = tid & 31;
    const int ch  = tid >> 5;      // 0..7
    float s = 0.f;
    #pragma unroll
    for (int b = 0; b < NBANK / 8; ++b)
        s += acc[(ch * (NBANK / 8) + b) * 32 + c];
    partial[ch][c] = s;
    __syncthreads();
    if (tid < 32) {
        float t = 0.f;
        #pragma unroll
        for (int k = 0; k < 8; ++k) t += partial[k][tid];
        col[tid] = t;
    }
    __syncthreads();
    if (tid == 0) {
        float sum = 0.f;
        #pragma unroll
        for (int e = 0; e < N_EXPERT; ++e)
            sum += col[e] * col[16 + e];
        out[4 * N_TOKENS] = sum * (float)N_EXPERT
                          / ((float)N_TOKENS * (float)N_TOKENS);
    }
}

extern "C" void kernel_launch(void* const* d_in, const int* in_sizes, int n_in,
                              void* d_out, int out_size, void* d_ws, size_t ws_size,
                              hipStream_t stream)
{
    const float* inp = (const float*)d_in[0];
    const float* W   = (const float*)d_in[1];
    float* out = (float*)d_out;
    float* acc = (float*)d_ws;

    hipMemsetAsync(acc, 0, NBANK * 32 * sizeof(float), stream);
    gate_kernel<<<NBLK, 256, 0, stream>>>(inp, W, out, acc);
    loss_kernel<<<1, 256, 0, stream>>>(acc, out);
}